// Round 4
// baseline (96.261 us; speedup 1.0000x reference)
//
#include <hip/hip_runtime.h>

typedef unsigned short u16;
typedef unsigned int u32;
typedef __attribute__((ext_vector_type(8))) short bf16x8;
typedef __attribute__((ext_vector_type(4))) float f32x4;

#define Bn 4
#define Cn 128
#define Hn 512
#define Ln 8000
#define EPSf 1e-8f

__device__ __forceinline__ float bf2f(u32 v) { return __uint_as_float(v << 16); }
__device__ __forceinline__ u32 f2bf(float f) {
  u32 u = __float_as_uint(f);
  return (u + 0x7fffu + ((u >> 16) & 1u)) >> 16;
}
__device__ __forceinline__ void gl16(const void* g, void* l) {
  __builtin_amdgcn_global_load_lds((const __attribute__((address_space(1))) u32*)g,
                                   (__attribute__((address_space(3))) u32*)l, 16, 0, 0);
}

// hT layout: row (b,l) = 1024 B (512 h bf16). Within each 128-B kt-slice (64 h),
// 16-B unit u holds h-group (u ^ ((l+4)&7)) of that slice. (XOR baked at k1 store.)

// ---------------- k0: weight prep (bf16 + pre-swizzled images) ----------------
__global__ void k0_prep(const float* __restrict__ W1, const float* __restrict__ Wout,
                        const float* __restrict__ Wskip,
                        u16* __restrict__ W1b, u16* __restrict__ Wcatb,
                        float* __restrict__ Wsum)
{
  const int bid = blockIdx.x, tid = threadIdx.x;
  if (bid < 64) {
    const int base = (bid * 256 + tid) * 4;
#pragma unroll
    for (int t = 0; t < 4; ++t) {
      int i = base + t;            // 0..65535
      int h = i >> 7, k = i & 127;
      int dbyte = h * 256 + (((k * 2) ^ ((h & 7) << 4)));
      W1b[dbyte >> 1] = (u16)f2bf(W1[h * Cn + k]);
    }
  } else if (bid < 192) {
    const int base = ((bid - 64) * 256 + tid) * 4;
#pragma unroll
    for (int t = 0; t < 4; ++t) {
      int j = base + t;            // 0..131071
      int kt = j >> 14, r = j & 16383, c = r >> 6, kk = r & 63;
      int k = kt * 64 + kk;
      float v = (c < Cn) ? Wout[c * Hn + k] : Wskip[(c - Cn) * Hn + k];
      int dbyte = kt * 32768 + c * 128 + (((kk * 2) ^ ((c & 7) << 4)));
      Wcatb[dbyte >> 1] = (u16)f2bf(v);
    }
  } else {
    const int c = tid;
    const float* Wp = (c < Cn) ? (Wout + (size_t)c * Hn) : (Wskip + (size_t)(c - Cn) * Hn);
    float s = 0.f;
    for (int k = 0; k < Hn; ++k) s += Wp[k];
    Wsum[c] = s;
  }
}

// ---------------- k1: fused transpose + GEMM1 (h = prelu(W1@x+b1)) ----------------
__global__ __launch_bounds__(256, 2)
void k1_fused(const float* __restrict__ x, const u16* __restrict__ W1b,
              const float* __restrict__ b1, const float* __restrict__ a1p,
              u16* __restrict__ hT, float* __restrict__ sum1, float* __restrict__ sumsq1)
{
  __shared__ char regA[32768];   // x f32 tile [128 c][256B], then W1 slice buffer
  __shared__ char xs[16384];     // [64 l][128 c bf16], 16B-unit swizzle by (l&7)
  __shared__ char stg[16384];    // 4 KB per wave store staging
  __shared__ float b1s[512];
  const int bidx = blockIdx.x;
  const int b = bidx / 125, l0 = (bidx % 125) * 64;
  const int tid = threadIdx.x, ln = tid & 63, w = tid >> 6;
  const int ln15 = ln & 15, lq = ln >> 4;

  {
    const char* xb = (const char*)x + ((size_t)b * Cn * Ln + l0) * 4;
#pragma unroll
    for (int i = 0; i < 8; ++i) {
      int chunk = w * 8 + i;                     // 0..31, 4 c-rows each
      gl16(xb + (size_t)(chunk * 4 + (ln >> 4)) * (Ln * 4) + (ln & 15) * 16,
           regA + chunk * 1024);
    }
  }
  b1s[tid] = b1[tid];
  b1s[tid + 256] = b1[tid + 256];
  __syncthreads();
  // transpose regA -> xs (bf16, swizzled)
#pragma unroll
  for (int p = 0; p < 4; ++p) {
    int u = tid + p * 256;
    int l = u & 63, ui = u >> 6;                 // ui 0..15
    u32 pk[4];
#pragma unroll
    for (int pp = 0; pp < 4; ++pp) {
      int c0 = ui * 8 + pp * 2;
      float f0 = *(const float*)(regA + c0 * 256 + l * 4);
      float f1 = *(const float*)(regA + (c0 + 1) * 256 + l * 4);
      pk[pp] = f2bf(f0) | (f2bf(f1) << 16);
    }
    uint4 st; st.x = pk[0]; st.y = pk[1]; st.z = pk[2]; st.w = pk[3];
    *(uint4*)(xs + l * 256 + ((ui * 16) ^ ((l & 7) << 4))) = st;
  }

  const float a1v = a1p[0];
  float sAcc = 0.f, qAcc = 0.f;

  for (int s = 0; s < 4; ++s) {
    __syncthreads();               // regA free (transpose / previous slice done)
#pragma unroll
    for (int i = 0; i < 8; ++i) {
      int chunk = w * 8 + i;
      gl16((const char*)W1b + s * 32768 + chunk * 1024 + ln * 16, regA + chunk * 1024);
    }
    __syncthreads();               // slice staged (barrier drains vmcnt)

    f32x4 acc[8];
    const f32x4 z4 = {0.f, 0.f, 0.f, 0.f};
#pragma unroll
    for (int rf = 0; rf < 8; ++rf) acc[rf] = z4;
#pragma unroll
    for (int kf = 0; kf < 4; ++kf) {
      const int brow = w * 16 + ln15;
      bf16x8 bfr = *(const bf16x8*)(xs + brow * 256 +
                                    ((kf * 64 + lq * 16) ^ ((brow & 7) << 4)));
#pragma unroll
      for (int rf = 0; rf < 8; ++rf) {
        int arow = rf * 16 + ln15;
        bf16x8 afr = *(const bf16x8*)(regA + arow * 256 +
                                      ((kf * 64 + lq * 16) ^ ((arow & 7) << 4)));
        acc[rf] = __builtin_amdgcn_mfma_f32_16x16x32_bf16(afr, bfr, acc[rf], 0, 0, 0);
      }
    }
    // epilogue: bias + prelu + sums; pack to stg (wave-private, swizzled)
#pragma unroll
    for (int rf = 0; rf < 8; ++rf) {
      int hb = s * 128 + rf * 16 + lq * 4;
      float v0 = acc[rf][0] + b1s[hb + 0]; v0 = v0 >= 0.f ? v0 : a1v * v0;
      float v1 = acc[rf][1] + b1s[hb + 1]; v1 = v1 >= 0.f ? v1 : a1v * v1;
      float v2 = acc[rf][2] + b1s[hb + 2]; v2 = v2 >= 0.f ? v2 : a1v * v2;
      float v3 = acc[rf][3] + b1s[hb + 3]; v3 = v3 >= 0.f ? v3 : a1v * v3;
      sAcc += v0 + v1 + v2 + v3;
      qAcc += v0 * v0 + v1 * v1 + v2 * v2 + v3 * v3;
      uint2 st2;
      st2.x = f2bf(v0) | (f2bf(v1) << 16);
      st2.y = f2bf(v2) | (f2bf(v3) << 16);
      *(uint2*)(stg + w * 4096 + ln15 * 256 +
                ((rf * 32 + lq * 8) ^ ((ln15 & 3) << 4))) = st2;
    }
    // coalesced 256B-chunk stores of wave's 16 rows (with baked kt-slice swizzle)
#pragma unroll
    for (int p = 0; p < 4; ++p) {
      int lr = p * 4 + (ln >> 4);
      int j = ln & 15;
      uint4 v = *(const uint4*)(stg + w * 4096 + lr * 256 + ((j * 16) ^ ((lr & 3) << 4)));
      int jp = (j & 8) | ((j & 7) ^ ((lr + 4) & 7));
      *(uint4*)((char*)hT + ((size_t)(b * Ln + l0 + w * 16 + lr)) * 1024 +
                s * 256 + jp * 16) = v;
    }
  }
  // per-l sums: reduce over the 4 lq lanes
  sAcc += __shfl_xor(sAcc, 16); qAcc += __shfl_xor(qAcc, 16);
  sAcc += __shfl_xor(sAcc, 32); qAcc += __shfl_xor(qAcc, 32);
  if (lq == 0) {
    sum1[b * Ln + l0 + w * 16 + ln15] = sAcc;
    sumsq1[b * Ln + l0 + w * 16 + ln15] = qAcc;
  }
}

// ---------------- k2: causal scan -> mean/rstd (single-pass, register-blocked) ----------------
__global__ void k2_scan(const float* __restrict__ sum, const float* __restrict__ sumsq,
                        float* __restrict__ mean, float* __restrict__ rstd)
{
  const int b = blockIdx.x, tid = threadIdx.x;
  const int lane = tid & 63, w = tid >> 6;
  __shared__ float wts[4], wtq[4];
  float v[32], q[32];
  float ts = 0.f, tq = 0.f;
  const int base = tid * 32;                    // threads 0..249 cover 8000
  const bool act = (tid < 250);
  if (act) {
#pragma unroll
    for (int i = 0; i < 8; ++i) {
      float4 a = *(const float4*)(sum + (size_t)b * Ln + base + i * 4);
      float4 c = *(const float4*)(sumsq + (size_t)b * Ln + base + i * 4);
      v[i * 4 + 0] = a.x; v[i * 4 + 1] = a.y; v[i * 4 + 2] = a.z; v[i * 4 + 3] = a.w;
      q[i * 4 + 0] = c.x; q[i * 4 + 1] = c.y; q[i * 4 + 2] = c.z; q[i * 4 + 3] = c.w;
    }
#pragma unroll
    for (int i = 0; i < 32; ++i) { ts += v[i]; tq += q[i]; }
  }
  float is = ts, iq = tq;
#pragma unroll
  for (int off = 1; off < 64; off <<= 1) {
    float a = __shfl_up(is, off);
    float c = __shfl_up(iq, off);
    if (lane >= off) { is += a; iq += c; }
  }
  float es = is - ts, eq = iq - tq;             // exclusive prefix within wave
  if (lane == 63) { wts[w] = is; wtq[w] = iq; }
  __syncthreads();
  for (int ww = 0; ww < w; ++ww) { es += wts[ww]; eq += wtq[ww]; }
  if (act) {
    float rs = es, rq = eq;
#pragma unroll
    for (int i = 0; i < 32; ++i) {
      rs += v[i]; rq += q[i];
      float cnt = 512.f * (float)(base + i + 1);
      float mn = rs / cnt;
      float var = fmaxf(rq / cnt - mn * mn, 0.f);
      v[i] = mn;
      q[i] = rsqrtf(var + EPSf);
    }
#pragma unroll
    for (int i = 0; i < 8; ++i) {
      float4 a; a.x = v[i*4+0]; a.y = v[i*4+1]; a.z = v[i*4+2]; a.w = v[i*4+3];
      float4 c; c.x = q[i*4+0]; c.y = q[i*4+1]; c.z = q[i*4+2]; c.w = q[i*4+3];
      *(float4*)(mean + (size_t)b * Ln + base + i * 4) = a;
      *(float4*)(rstd + (size_t)b * Ln + base + i * 4) = c;
    }
  }
}

// ---------------- k3: sums of g = prelu(dwconv(cln1(h))) only (no g store) ----------------
__global__ __launch_bounds__(256, 2)
void k3_sums(const u16* __restrict__ hT, const float* __restrict__ mean1,
             const float* __restrict__ rstd1, const float* __restrict__ dw,
             const float* __restrict__ db, const float* __restrict__ a2p,
             float* __restrict__ sum2, float* __restrict__ sumsq2)
{
  __shared__ char hTs[73728];       // 72 rows x 1KB
  __shared__ float m1s[72], r1s[72];
  const int bidx = blockIdx.x;
  const int b = bidx / 125;
  const int l0 = (bidx % 125) * 64;
  const int tid = threadIdx.x;
  const int ln = tid & 63, w = tid >> 6;

  for (int i = 0; i < 18; ++i) {
    int chunk = w * 18 + i;
    int lr = l0 - 4 + chunk;
    int lc = lr < 0 ? 0 : (lr > Ln - 1 ? Ln - 1 : lr);
    gl16((const char*)hT + ((size_t)(b * Ln + lc)) * 1024 + ln * 16, hTs + chunk * 1024);
  }
  if (tid < 72) {
    int lr = l0 - 4 + tid;
    bool ok = (lr >= 0) && (lr < Ln);
    m1s[tid] = ok ? mean1[b * Ln + lr] : 0.f;
    r1s[tid] = ok ? rstd1[b * Ln + lr] : 0.f;
  }
  float d0[8], d1[8], d2[8], dbv[8];
#pragma unroll
  for (int e = 0; e < 8; ++e) {
    int hh = ln * 8 + e;
    d0[e] = dw[hh * 3 + 0]; d1[e] = dw[hh * 3 + 1]; d2[e] = dw[hh * 3 + 2];
    dbv[e] = db[hh];
  }
  const float a2v = a2p[0];
  __syncthreads();

  const int gB = (ln & 56) << 4;    // base byte of this thread's 8-unit block
  for (int it = 0; it < 16; ++it) {
    const int llo = w * 16 + it;      // local out row 0..63
    const int l = l0 + llo;
    uint4 t0 = *(const uint4*)(hTs + (size_t)(llo) * 1024 + gB + (((ln ^ llo) & 7) << 4));
    uint4 t1 = *(const uint4*)(hTs + (size_t)(llo + 4) * 1024 + gB + (((ln ^ (llo + 4)) & 7) << 4));
    uint4 t2 = *(const uint4*)(hTs + (size_t)(llo + 8) * 1024 + gB + (((ln ^ llo) & 7) << 4));
    const float m0 = m1s[llo],     rr0 = r1s[llo];
    const float mC = m1s[llo + 4], rrC = r1s[llo + 4];
    const float m2v = m1s[llo + 8], rr2 = r1s[llo + 8];
    const u32* p0 = reinterpret_cast<const u32*>(&t0);
    const u32* p1 = reinterpret_cast<const u32*>(&t1);
    const u32* p2 = reinterpret_cast<const u32*>(&t2);
    float sv = 0.f, qv = 0.f;
#pragma unroll
    for (int pp = 0; pp < 4; ++pp) {
#pragma unroll
      for (int hi = 0; hi < 2; ++hi) {
        int e = pp * 2 + hi;
        u32 a0 = hi ? (p0[pp] >> 16) : (p0[pp] & 0xffffu);
        u32 a1b = hi ? (p1[pp] >> 16) : (p1[pp] & 0xffffu);
        u32 a2b = hi ? (p2[pp] >> 16) : (p2[pp] & 0xffffu);
        float nh0 = (bf2f(a0) - m0) * rr0;
        float nh1 = (bf2f(a1b) - mC) * rrC;
        float nh2 = (bf2f(a2b) - m2v) * rr2;
        float vv = fmaf(d0[e], nh0, fmaf(d1[e], nh1, fmaf(d2[e], nh2, dbv[e])));
        vv = vv >= 0.f ? vv : a2v * vv;
        sv += vv; qv += vv * vv;
      }
    }
#pragma unroll
    for (int off = 1; off < 64; off <<= 1) {
      sv += __shfl_xor(sv, off);
      qv += __shfl_xor(qv, off);
    }
    if (ln == 0) {
      sum2[b * Ln + l] = sv;
      sumsq2[b * Ln + l] = qv;
    }
  }
}

// ---------------- k5: recompute g per K-tile + MFMA GEMM + folded cln2 + residual ----------------
__global__ __launch_bounds__(256, 2)
void k5_fused(const u16* __restrict__ hT, const u16* __restrict__ Wcatb,
              const float* __restrict__ Wsum, const float* __restrict__ bout,
              const float* __restrict__ bskip,
              const float* __restrict__ mean1, const float* __restrict__ rstd1,
              const float* __restrict__ mean2, const float* __restrict__ rstd2,
              const float* __restrict__ dw, const float* __restrict__ db,
              const float* __restrict__ a2p,
              const float* __restrict__ x, float* __restrict__ outp)
{
  __shared__ char Ab[32768];     // Wcat kt tile [256 c][64 k bf16] (swizzled image); epilogue stg
  __shared__ char Hb[9216];      // hT slice: 72 rows x 128 B (raw swizzled bytes)
  __shared__ char Gb[8192];      // g tile [64 l][64 h bf16] (unit ^= l&7)
  __shared__ float dwdb[2048];   // [512 h][d0,d1,d2,db]
  __shared__ float m1s[72], r1s[72];

  const int bidx = blockIdx.x;
  const int b = bidx / 125;
  const int l0 = (bidx % 125) * 64;
  const int tid = threadIdx.x;
  const int ln = tid & 63, w = tid >> 6;
  const int ln15 = ln & 15, lq = ln >> 4;

  auto stageH = [&](int kt) {
    for (int ch = w; ch < 9; ch += 4) {
      int row = ch * 8 + (ln >> 3);
      int lr = l0 - 4 + row;
      int lc = lr < 0 ? 0 : (lr > Ln - 1 ? Ln - 1 : lr);
      gl16((const char*)hT + ((size_t)(b * Ln + lc)) * 1024 + kt * 128 + (ln & 7) * 16,
           Hb + ch * 1024);
    }
  };
  auto stageA = [&](int kt) {
    const char* Asrc = (const char*)Wcatb + kt * 32768;
#pragma unroll
    for (int i = 0; i < 8; ++i) {
      int chunk = w * 8 + i;
      gl16(Asrc + chunk * 1024 + ln * 16, Ab + chunk * 1024);
    }
  };

  // prologue staging
  stageA(0);
  stageH(0);
  if (tid < 72) {
    int lr = l0 - 4 + tid;
    bool ok = (lr >= 0) && (lr < Ln);
    m1s[tid] = ok ? mean1[b * Ln + lr] : 0.f;
    r1s[tid] = ok ? rstd1[b * Ln + lr] : 0.f;
  }
  {
    int h2 = tid * 2;
    dwdb[h2 * 4 + 0] = dw[h2 * 3 + 0];
    dwdb[h2 * 4 + 1] = dw[h2 * 3 + 1];
    dwdb[h2 * 4 + 2] = dw[h2 * 3 + 2];
    dwdb[h2 * 4 + 3] = db[h2];
    dwdb[h2 * 4 + 4] = dw[h2 * 3 + 3];
    dwdb[h2 * 4 + 5] = dw[h2 * 3 + 4];
    dwdb[h2 * 4 + 6] = dw[h2 * 3 + 5];
    dwdb[h2 * 4 + 7] = db[h2 + 1];
  }
  const float a2v = a2p[0];
  __syncthreads();

  f32x4 acc[4][4];
  const f32x4 z4 = {0.f, 0.f, 0.f, 0.f};
#pragma unroll
  for (int i = 0; i < 4; ++i)
#pragma unroll
    for (int j = 0; j < 4; ++j) acc[i][j] = z4;
  const int c0w = w * 64;

  for (int kt = 0; kt < 8; ++kt) {
    // ---- compute G(kt) from Hb ----
    {
      const int r0 = ln, r1 = ln + 4, r2 = ln + 8;
      const float m0 = m1s[r0], q0 = r1s[r0];
      const float mA = m1s[r1], qA = r1s[r1];
      const float mB = m1s[r2], qB = r1s[r2];
      const int kk0 = r0 & 7, kk1 = r1 & 7;
#pragma unroll
      for (int uu = 0; uu < 2; ++uu) {
        const int grp = w + uu * 4;
        uint4 t0 = *(const uint4*)(Hb + r0 * 128 + ((grp ^ kk0) << 4));
        uint4 t1 = *(const uint4*)(Hb + r1 * 128 + ((grp ^ kk1) << 4));
        uint4 t2 = *(const uint4*)(Hb + r2 * 128 + ((grp ^ kk0) << 4));
        const u32* p0 = (const u32*)&t0;
        const u32* p1 = (const u32*)&t1;
        const u32* p2 = (const u32*)&t2;
        u32 ow[4];
#pragma unroll
        for (int pp = 0; pp < 4; ++pp) {
          float vv[2];
#pragma unroll
          for (int hi = 0; hi < 2; ++hi) {
            const int e = pp * 2 + hi;
            float4 dv = *(const float4*)(&dwdb[(kt * 64 + grp * 8 + e) * 4]);
            u32 a0 = hi ? (p0[pp] >> 16) : (p0[pp] & 0xffffu);
            u32 a1 = hi ? (p1[pp] >> 16) : (p1[pp] & 0xffffu);
            u32 a2b = hi ? (p2[pp] >> 16) : (p2[pp] & 0xffffu);
            float nh0 = (bf2f(a0) - m0) * q0;
            float nh1 = (bf2f(a1) - mA) * qA;
            float nh2 = (bf2f(a2b) - mB) * qB;
            float v = fmaf(dv.x, nh0, fmaf(dv.y, nh1, fmaf(dv.z, nh2, dv.w)));
            vv[hi] = v >= 0.f ? v : a2v * v;
          }
          ow[pp] = f2bf(vv[0]) | (f2bf(vv[1]) << 16);
        }
        uint4 st; st.x = ow[0]; st.y = ow[1]; st.z = ow[2]; st.w = ow[3];
        *(uint4*)(Gb + ln * 128 + ((grp ^ (ln & 7)) << 4)) = st;
      }
    }
    __syncthreads();               // G visible; A(kt) drained
    if (kt < 7) stageH(kt + 1);    // overlaps MFMA below
    // ---- GEMM(kt) ----
#pragma unroll
    for (int ks = 0; ks < 2; ++ks) {
      bf16x8 bfr[4];
#pragma unroll
      for (int cf = 0; cf < 4; ++cf) {
        int brow = cf * 16 + ln15;
        int off = ((ks * 64 + lq * 16) ^ ((brow & 7) << 4));
        bfr[cf] = *(const bf16x8*)(Gb + brow * 128 + off);
      }
#pragma unroll
      for (int rf = 0; rf < 4; ++rf) {
        int arow = c0w + rf * 16 + ln15;
        int aoff = ((ks * 64 + lq * 16) ^ ((arow & 7) << 4));
        bf16x8 afr = *(const bf16x8*)(Ab + arow * 128 + aoff);
#pragma unroll
        for (int cf = 0; cf < 4; ++cf)
          acc[rf][cf] = __builtin_amdgcn_mfma_f32_16x16x32_bf16(afr, bfr[cf], acc[rf][cf], 0, 0, 0);
      }
    }
    __syncthreads();               // GEMM done (A free), H(kt+1) drained
    if (kt < 7) stageA(kt + 1);    // overlaps next computeG
  }

  // ---- epilogue: fold cln2 + biases, stage 32KB halves in Ab, coalesced stores ----
  float wsr[4][4], bir[4][4];
#pragma unroll
  for (int rf = 0; rf < 4; ++rf)
#pragma unroll
    for (int r = 0; r < 4; ++r) {
      int c = c0w + rf * 16 + lq * 4 + r;
      wsr[rf][r] = Wsum[c];
      bir[rf][r] = (c < Cn) ? bout[c] : bskip[c - Cn];
    }
  const size_t OUTOFF = (size_t)Bn * Cn * Ln;
  char* stg = Ab;
#pragma unroll
  for (int p = 0; p < 2; ++p) {
    if (p) __syncthreads();        // previous store pass done
#pragma unroll
    for (int cc = 0; cc < 2; ++cc) {
      const int cf = p * 2 + cc;
      const int ll = cc * 16 + ln15;        // 0..31
      const int l = l0 + cf * 16 + ln15;
      const float m2 = mean2[b * Ln + l];
      const float r2 = rstd2[b * Ln + l];
#pragma unroll
      for (int rf = 0; rf < 4; ++rf) {
#pragma unroll
        for (int r = 0; r < 4; ++r) {
          int c = c0w + rf * 16 + lq * 4 + r;
          float o = r2 * (acc[rf][cf][r] - m2 * wsr[rf][r]) + bir[rf][r];
          *(float*)(stg + c * 128 + ((((ll >> 2) ^ (c & 7)) << 4)) + (ll & 3) * 4) = o;
        }
      }
    }
    __syncthreads();
#pragma unroll
    for (int pp = 0; pp < 8; ++pp) {
      int i = pp * 256 + tid;
      int c = i >> 3, j = i & 7;
      float4 v = *(const float4*)(stg + c * 128 + (((j ^ (c & 7)) << 4)));
      int lcol = l0 + p * 32 + j * 4;
      if (c < Cn) {
        float4 xv = *(const float4*)(x + ((size_t)(b * Cn + c)) * Ln + lcol);
        v.x += xv.x; v.y += xv.y; v.z += xv.z; v.w += xv.w;
        *(float4*)(outp + ((size_t)(b * Cn + c)) * Ln + lcol) = v;
      } else {
        *(float4*)(outp + OUTOFF + ((size_t)(b * Cn + c - Cn)) * Ln + lcol) = v;
      }
    }
  }
}

extern "C" void kernel_launch(void* const* d_in, const int* in_sizes, int n_in,
                              void* d_out, int out_size, void* d_ws, size_t ws_size,
                              hipStream_t stream)
{
  const float* x     = (const float*)d_in[0];
  const float* W1    = (const float*)d_in[1];
  const float* b1    = (const float*)d_in[2];
  const float* dw    = (const float*)d_in[3];
  const float* db    = (const float*)d_in[4];
  const float* Wout  = (const float*)d_in[5];
  const float* bout  = (const float*)d_in[6];
  const float* Wskip = (const float*)d_in[7];
  const float* bskip = (const float*)d_in[8];
  const float* a1    = (const float*)d_in[9];
  const float* a2    = (const float*)d_in[10];
  float* outp = (float*)d_out;

  char* ws = (char*)d_ws;
  u16* hT     = (u16*)(ws);                  // 32,768,000 B
  u16* W1b    = (u16*)(ws + 65536000);       // 131,072 B
  u16* Wcatb  = (u16*)(ws + 65667072);       // 262,144 B
  float* Wsum   = (float*)(ws + 65929216);   // 1,024 B
  float* sum1   = (float*)(ws + 65930240);
  float* sumsq1 = (float*)(ws + 66058240);
  float* mean1  = (float*)(ws + 66186240);
  float* rstd1  = (float*)(ws + 66314240);
  float* sum2   = (float*)(ws + 66442240);
  float* sumsq2 = (float*)(ws + 66570240);
  float* mean2  = (float*)(ws + 66698240);
  float* rstd2  = (float*)(ws + 66826240);
  (void)in_sizes; (void)n_in; (void)out_size; (void)ws_size;

  hipLaunchKernelGGL(k0_prep, dim3(193), dim3(256), 0, stream,
                     W1, Wout, Wskip, W1b, Wcatb, Wsum);
  hipLaunchKernelGGL(k1_fused, dim3(Bn * 125), dim3(256), 0, stream,
                     x, W1b, b1, a1, hT, sum1, sumsq1);
  hipLaunchKernelGGL(k2_scan, dim3(Bn), dim3(256), 0, stream,
                     sum1, sumsq1, mean1, rstd1);
  hipLaunchKernelGGL(k3_sums, dim3(Bn * 125), dim3(256), 0, stream,
                     hT, mean1, rstd1, dw, db, a2, sum2, sumsq2);
  hipLaunchKernelGGL(k2_scan, dim3(Bn), dim3(256), 0, stream,
                     sum2, sumsq2, mean2, rstd2);
  hipLaunchKernelGGL(k5_fused, dim3(Bn * 125), dim3(256), 0, stream,
                     hT, Wcatb, Wsum, bout, bskip, mean1, rstd1, mean2, rstd2,
                     dw, db, a2, x, outp);
}

// Round 5
// 95.904 us; speedup vs baseline: 1.0037x; 1.0037x over previous
//
#include <hip/hip_runtime.h>

typedef unsigned short u16;
typedef unsigned int u32;
typedef __attribute__((ext_vector_type(8))) short bf16x8;
typedef __attribute__((ext_vector_type(4))) float f32x4;

#define Bn 4
#define Cn 128
#define Hn 512
#define Ln 8000
#define EPSf 1e-8f

__device__ __forceinline__ float bf2f(u32 v) { return __uint_as_float(v << 16); }
__device__ __forceinline__ u32 f2bf(float f) {
  u32 u = __float_as_uint(f);
  return (u + 0x7fffu + ((u >> 16) & 1u)) >> 16;
}
__device__ __forceinline__ void gl16(const void* g, void* l) {
  __builtin_amdgcn_global_load_lds((const __attribute__((address_space(1))) u32*)g,
                                   (__attribute__((address_space(3))) u32*)l, 16, 0, 0);
}

// hT layout: row (b,l) = 1024 B (512 h bf16). Within each 128-B kt-slice (64 h),
// 16-B unit u holds h-group (u ^ ((l+4)&7)) of that slice. (XOR baked at k1 store.)

// ---------------- k0: weight prep (bf16 + pre-swizzled images) ----------------
__global__ void k0_prep(const float* __restrict__ W1, const float* __restrict__ Wout,
                        const float* __restrict__ Wskip,
                        u16* __restrict__ W1b, u16* __restrict__ Wcatb,
                        float* __restrict__ Wsum)
{
  const int bid = blockIdx.x, tid = threadIdx.x;
  if (bid < 64) {
    const int base = (bid * 256 + tid) * 4;
#pragma unroll
    for (int t = 0; t < 4; ++t) {
      int i = base + t;            // 0..65535
      int h = i >> 7, k = i & 127;
      int dbyte = h * 256 + (((k * 2) ^ ((h & 7) << 4)));
      W1b[dbyte >> 1] = (u16)f2bf(W1[h * Cn + k]);
    }
  } else if (bid < 192) {
    const int base = ((bid - 64) * 256 + tid) * 4;
#pragma unroll
    for (int t = 0; t < 4; ++t) {
      int j = base + t;            // 0..131071
      int kt = j >> 14, r = j & 16383, c = r >> 6, kk = r & 63;
      int k = kt * 64 + kk;
      float v = (c < Cn) ? Wout[c * Hn + k] : Wskip[(c - Cn) * Hn + k];
      int dbyte = kt * 32768 + c * 128 + (((kk * 2) ^ ((c & 7) << 4)));
      Wcatb[dbyte >> 1] = (u16)f2bf(v);
    }
  } else {
    const int c = tid;
    const float* Wp = (c < Cn) ? (Wout + (size_t)c * Hn) : (Wskip + (size_t)(c - Cn) * Hn);
    float s = 0.f;
    for (int k = 0; k < Hn; ++k) s += Wp[k];
    Wsum[c] = s;
  }
}

// ---------------- k1: fused transpose + GEMM1 (h = prelu(W1@x+b1)) ----------------
__global__ __launch_bounds__(256, 2)
void k1_fused(const float* __restrict__ x, const u16* __restrict__ W1b,
              const float* __restrict__ b1, const float* __restrict__ a1p,
              u16* __restrict__ hT, float* __restrict__ sum1, float* __restrict__ sumsq1)
{
  __shared__ char regA[32768];   // x f32 tile [128 c][256B], then W1 slice buffer
  __shared__ char xs[16384];     // [64 l][128 c bf16], 16B-unit swizzle by (l&7)
  __shared__ char stg[16384];    // 4 KB per wave store staging
  __shared__ float b1s[512];
  const int bidx = blockIdx.x;
  const int b = bidx / 125, l0 = (bidx % 125) * 64;
  const int tid = threadIdx.x, ln = tid & 63, w = tid >> 6;
  const int ln15 = ln & 15, lq = ln >> 4;

  {
    const char* xb = (const char*)x + ((size_t)b * Cn * Ln + l0) * 4;
#pragma unroll
    for (int i = 0; i < 8; ++i) {
      int chunk = w * 8 + i;                     // 0..31, 4 c-rows each
      gl16(xb + (size_t)(chunk * 4 + (ln >> 4)) * (Ln * 4) + (ln & 15) * 16,
           regA + chunk * 1024);
    }
  }
  b1s[tid] = b1[tid];
  b1s[tid + 256] = b1[tid + 256];
  __syncthreads();
  // transpose regA -> xs (bf16, swizzled)
#pragma unroll
  for (int p = 0; p < 4; ++p) {
    int u = tid + p * 256;
    int l = u & 63, ui = u >> 6;                 // ui 0..15
    u32 pk[4];
#pragma unroll
    for (int pp = 0; pp < 4; ++pp) {
      int c0 = ui * 8 + pp * 2;
      float f0 = *(const float*)(regA + c0 * 256 + l * 4);
      float f1 = *(const float*)(regA + (c0 + 1) * 256 + l * 4);
      pk[pp] = f2bf(f0) | (f2bf(f1) << 16);
    }
    uint4 st; st.x = pk[0]; st.y = pk[1]; st.z = pk[2]; st.w = pk[3];
    *(uint4*)(xs + l * 256 + ((ui * 16) ^ ((l & 7) << 4))) = st;
  }

  const float a1v = a1p[0];
  float sAcc = 0.f, qAcc = 0.f;

  for (int s = 0; s < 4; ++s) {
    __syncthreads();               // regA free (transpose / previous slice done)
#pragma unroll
    for (int i = 0; i < 8; ++i) {
      int chunk = w * 8 + i;
      gl16((const char*)W1b + s * 32768 + chunk * 1024 + ln * 16, regA + chunk * 1024);
    }
    __syncthreads();               // slice staged (barrier drains vmcnt)

    f32x4 acc[8];
    const f32x4 z4 = {0.f, 0.f, 0.f, 0.f};
#pragma unroll
    for (int rf = 0; rf < 8; ++rf) acc[rf] = z4;
#pragma unroll
    for (int kf = 0; kf < 4; ++kf) {
      const int brow = w * 16 + ln15;
      bf16x8 bfr = *(const bf16x8*)(xs + brow * 256 +
                                    ((kf * 64 + lq * 16) ^ ((brow & 7) << 4)));
#pragma unroll
      for (int rf = 0; rf < 8; ++rf) {
        int arow = rf * 16 + ln15;
        bf16x8 afr = *(const bf16x8*)(regA + arow * 256 +
                                      ((kf * 64 + lq * 16) ^ ((arow & 7) << 4)));
        acc[rf] = __builtin_amdgcn_mfma_f32_16x16x32_bf16(afr, bfr, acc[rf], 0, 0, 0);
      }
    }
    // epilogue: bias + prelu + sums; pack to stg (wave-private, swizzled)
#pragma unroll
    for (int rf = 0; rf < 8; ++rf) {
      int hb = s * 128 + rf * 16 + lq * 4;
      float v0 = acc[rf][0] + b1s[hb + 0]; v0 = v0 >= 0.f ? v0 : a1v * v0;
      float v1 = acc[rf][1] + b1s[hb + 1]; v1 = v1 >= 0.f ? v1 : a1v * v1;
      float v2 = acc[rf][2] + b1s[hb + 2]; v2 = v2 >= 0.f ? v2 : a1v * v2;
      float v3 = acc[rf][3] + b1s[hb + 3]; v3 = v3 >= 0.f ? v3 : a1v * v3;
      sAcc += v0 + v1 + v2 + v3;
      qAcc += v0 * v0 + v1 * v1 + v2 * v2 + v3 * v3;
      uint2 st2;
      st2.x = f2bf(v0) | (f2bf(v1) << 16);
      st2.y = f2bf(v2) | (f2bf(v3) << 16);
      *(uint2*)(stg + w * 4096 + ln15 * 256 +
                ((rf * 32 + lq * 8) ^ ((ln15 & 3) << 4))) = st2;
    }
    // coalesced 256B-chunk stores of wave's 16 rows (with baked kt-slice swizzle)
#pragma unroll
    for (int p = 0; p < 4; ++p) {
      int lr = p * 4 + (ln >> 4);
      int j = ln & 15;
      uint4 v = *(const uint4*)(stg + w * 4096 + lr * 256 + ((j * 16) ^ ((lr & 3) << 4)));
      int jp = (j & 8) | ((j & 7) ^ ((lr + 4) & 7));
      *(uint4*)((char*)hT + ((size_t)(b * Ln + l0 + w * 16 + lr)) * 1024 +
                s * 256 + jp * 16) = v;
    }
  }
  // per-l sums: reduce over the 4 lq lanes
  sAcc += __shfl_xor(sAcc, 16); qAcc += __shfl_xor(qAcc, 16);
  sAcc += __shfl_xor(sAcc, 32); qAcc += __shfl_xor(qAcc, 32);
  if (lq == 0) {
    sum1[b * Ln + l0 + w * 16 + ln15] = sAcc;
    sumsq1[b * Ln + l0 + w * 16 + ln15] = qAcc;
  }
}

// ---------------- k2: causal scan -> mean/rstd (single-pass, register-blocked) ----------------
__global__ void k2_scan(const float* __restrict__ sum, const float* __restrict__ sumsq,
                        float* __restrict__ mean, float* __restrict__ rstd)
{
  const int b = blockIdx.x, tid = threadIdx.x;
  const int lane = tid & 63, w = tid >> 6;
  __shared__ float wts[4], wtq[4];
  float v[32], q[32];
  float ts = 0.f, tq = 0.f;
  const int base = tid * 32;                    // threads 0..249 cover 8000
  const bool act = (tid < 250);
  if (act) {
#pragma unroll
    for (int i = 0; i < 8; ++i) {
      float4 a = *(const float4*)(sum + (size_t)b * Ln + base + i * 4);
      float4 c = *(const float4*)(sumsq + (size_t)b * Ln + base + i * 4);
      v[i * 4 + 0] = a.x; v[i * 4 + 1] = a.y; v[i * 4 + 2] = a.z; v[i * 4 + 3] = a.w;
      q[i * 4 + 0] = c.x; q[i * 4 + 1] = c.y; q[i * 4 + 2] = c.z; q[i * 4 + 3] = c.w;
    }
#pragma unroll
    for (int i = 0; i < 32; ++i) { ts += v[i]; tq += q[i]; }
  }
  float is = ts, iq = tq;
#pragma unroll
  for (int off = 1; off < 64; off <<= 1) {
    float a = __shfl_up(is, off);
    float c = __shfl_up(iq, off);
    if (lane >= off) { is += a; iq += c; }
  }
  float es = is - ts, eq = iq - tq;             // exclusive prefix within wave
  if (lane == 63) { wts[w] = is; wtq[w] = iq; }
  __syncthreads();
  for (int ww = 0; ww < w; ++ww) { es += wts[ww]; eq += wtq[ww]; }
  if (act) {
    float rs = es, rq = eq;
#pragma unroll
    for (int i = 0; i < 32; ++i) {
      rs += v[i]; rq += q[i];
      float cnt = 512.f * (float)(base + i + 1);
      float mn = rs / cnt;
      float var = fmaxf(rq / cnt - mn * mn, 0.f);
      v[i] = mn;
      q[i] = rsqrtf(var + EPSf);
    }
#pragma unroll
    for (int i = 0; i < 8; ++i) {
      float4 a; a.x = v[i*4+0]; a.y = v[i*4+1]; a.z = v[i*4+2]; a.w = v[i*4+3];
      float4 c; c.x = q[i*4+0]; c.y = q[i*4+1]; c.z = q[i*4+2]; c.w = q[i*4+3];
      *(float4*)(mean + (size_t)b * Ln + base + i * 4) = a;
      *(float4*)(rstd + (size_t)b * Ln + base + i * 4) = c;
    }
  }
}

// ---------------- k3: sums of g = prelu(dwconv(cln1(h))) only (no g store) ----------------
__global__ __launch_bounds__(256, 2)
void k3_sums(const u16* __restrict__ hT, const float* __restrict__ mean1,
             const float* __restrict__ rstd1, const float* __restrict__ dw,
             const float* __restrict__ db, const float* __restrict__ a2p,
             float* __restrict__ sum2, float* __restrict__ sumsq2)
{
  __shared__ char hTs[73728];       // 72 rows x 1KB
  __shared__ float m1s[72], r1s[72];
  const int bidx = blockIdx.x;
  const int b = bidx / 125;
  const int l0 = (bidx % 125) * 64;
  const int tid = threadIdx.x;
  const int ln = tid & 63, w = tid >> 6;

  for (int i = 0; i < 18; ++i) {
    int chunk = w * 18 + i;
    int lr = l0 - 4 + chunk;
    int lc = lr < 0 ? 0 : (lr > Ln - 1 ? Ln - 1 : lr);
    gl16((const char*)hT + ((size_t)(b * Ln + lc)) * 1024 + ln * 16, hTs + chunk * 1024);
  }
  if (tid < 72) {
    int lr = l0 - 4 + tid;
    bool ok = (lr >= 0) && (lr < Ln);
    m1s[tid] = ok ? mean1[b * Ln + lr] : 0.f;
    r1s[tid] = ok ? rstd1[b * Ln + lr] : 0.f;
  }
  float d0[8], d1[8], d2[8], dbv[8];
#pragma unroll
  for (int e = 0; e < 8; ++e) {
    int hh = ln * 8 + e;
    d0[e] = dw[hh * 3 + 0]; d1[e] = dw[hh * 3 + 1]; d2[e] = dw[hh * 3 + 2];
    dbv[e] = db[hh];
  }
  const float a2v = a2p[0];
  __syncthreads();

  const int gB = (ln & 56) << 4;    // base byte of this thread's 8-unit block
  for (int it = 0; it < 16; ++it) {
    const int llo = w * 16 + it;      // local out row 0..63
    const int l = l0 + llo;
    uint4 t0 = *(const uint4*)(hTs + (size_t)(llo) * 1024 + gB + (((ln ^ llo) & 7) << 4));
    uint4 t1 = *(const uint4*)(hTs + (size_t)(llo + 4) * 1024 + gB + (((ln ^ (llo + 4)) & 7) << 4));
    uint4 t2 = *(const uint4*)(hTs + (size_t)(llo + 8) * 1024 + gB + (((ln ^ llo) & 7) << 4));
    const float m0 = m1s[llo],     rr0 = r1s[llo];
    const float mC = m1s[llo + 4], rrC = r1s[llo + 4];
    const float m2v = m1s[llo + 8], rr2 = r1s[llo + 8];
    const u32* p0 = reinterpret_cast<const u32*>(&t0);
    const u32* p1 = reinterpret_cast<const u32*>(&t1);
    const u32* p2 = reinterpret_cast<const u32*>(&t2);
    float sv = 0.f, qv = 0.f;
#pragma unroll
    for (int pp = 0; pp < 4; ++pp) {
#pragma unroll
      for (int hi = 0; hi < 2; ++hi) {
        int e = pp * 2 + hi;
        u32 a0 = hi ? (p0[pp] >> 16) : (p0[pp] & 0xffffu);
        u32 a1b = hi ? (p1[pp] >> 16) : (p1[pp] & 0xffffu);
        u32 a2b = hi ? (p2[pp] >> 16) : (p2[pp] & 0xffffu);
        float nh0 = (bf2f(a0) - m0) * rr0;
        float nh1 = (bf2f(a1b) - mC) * rrC;
        float nh2 = (bf2f(a2b) - m2v) * rr2;
        float vv = fmaf(d0[e], nh0, fmaf(d1[e], nh1, fmaf(d2[e], nh2, dbv[e])));
        vv = vv >= 0.f ? vv : a2v * vv;
        sv += vv; qv += vv * vv;
      }
    }
#pragma unroll
    for (int off = 1; off < 64; off <<= 1) {
      sv += __shfl_xor(sv, off);
      qv += __shfl_xor(qv, off);
    }
    if (ln == 0) {
      sum2[b * Ln + l] = sv;
      sumsq2[b * Ln + l] = qv;
    }
  }
}

// ---------------- k5: recompute g per K-tile + MFMA GEMM + folded cln2 + residual ----------------
__global__ __launch_bounds__(256, 2)
void k5_fused(const u16* __restrict__ hT, const u16* __restrict__ Wcatb,
              const float* __restrict__ Wsum, const float* __restrict__ bout,
              const float* __restrict__ bskip,
              const float* __restrict__ mean1, const float* __restrict__ rstd1,
              const float* __restrict__ mean2, const float* __restrict__ rstd2,
              const float* __restrict__ dw, const float* __restrict__ db,
              const float* __restrict__ a2p,
              const float* __restrict__ x, float* __restrict__ outp)
{
  __shared__ char Ab[32768];     // Wcat kt tile [256 c][64 k bf16] (swizzled image); epilogue stg
  __shared__ char Hb[9216];      // hT slice: 72 rows x 128 B (raw swizzled bytes)
  __shared__ char Gb[8192];      // g tile [64 l][64 h bf16] (unit ^= l&7)
  __shared__ float dwdb[2048];   // [512 h][d0,d1,d2,db]
  __shared__ float m1s[72], r1s[72];

  const int bidx = blockIdx.x;
  const int b = bidx / 125;
  const int l0 = (bidx % 125) * 64;
  const int tid = threadIdx.x;
  const int ln = tid & 63, w = tid >> 6;
  const int ln15 = ln & 15, lq = ln >> 4;

  auto stageH = [&](int kt) {
    for (int ch = w; ch < 9; ch += 4) {
      int row = ch * 8 + (ln >> 3);
      int lr = l0 - 4 + row;
      int lc = lr < 0 ? 0 : (lr > Ln - 1 ? Ln - 1 : lr);
      gl16((const char*)hT + ((size_t)(b * Ln + lc)) * 1024 + kt * 128 + (ln & 7) * 16,
           Hb + ch * 1024);
    }
  };
  auto stageA = [&](int kt) {
    const char* Asrc = (const char*)Wcatb + kt * 32768;
#pragma unroll
    for (int i = 0; i < 8; ++i) {
      int chunk = w * 8 + i;
      gl16(Asrc + chunk * 1024 + ln * 16, Ab + chunk * 1024);
    }
  };

  // prologue staging
  stageA(0);
  stageH(0);
  if (tid < 72) {
    int lr = l0 - 4 + tid;
    bool ok = (lr >= 0) && (lr < Ln);
    m1s[tid] = ok ? mean1[b * Ln + lr] : 0.f;
    r1s[tid] = ok ? rstd1[b * Ln + lr] : 0.f;
  }
  {
    int h2 = tid * 2;
    dwdb[h2 * 4 + 0] = dw[h2 * 3 + 0];
    dwdb[h2 * 4 + 1] = dw[h2 * 3 + 1];
    dwdb[h2 * 4 + 2] = dw[h2 * 3 + 2];
    dwdb[h2 * 4 + 3] = db[h2];
    dwdb[h2 * 4 + 4] = dw[h2 * 3 + 3];
    dwdb[h2 * 4 + 5] = dw[h2 * 3 + 4];
    dwdb[h2 * 4 + 6] = dw[h2 * 3 + 5];
    dwdb[h2 * 4 + 7] = db[h2 + 1];
  }
  const float a2v = a2p[0];
  __syncthreads();

  f32x4 acc[4][4];
  const f32x4 z4 = {0.f, 0.f, 0.f, 0.f};
#pragma unroll
  for (int i = 0; i < 4; ++i)
#pragma unroll
    for (int j = 0; j < 4; ++j) acc[i][j] = z4;
  const int c0w = w * 64;

  for (int kt = 0; kt < 8; ++kt) {
    // ---- compute G(kt) from Hb ----
    {
      const int r0 = ln, r1 = ln + 4, r2 = ln + 8;
      const float m0 = m1s[r0], q0 = r1s[r0];
      const float mA = m1s[r1], qA = r1s[r1];
      const float mB = m1s[r2], qB = r1s[r2];
      const int kk0 = r0 & 7, kk1 = r1 & 7;
#pragma unroll
      for (int uu = 0; uu < 2; ++uu) {
        const int grp = w + uu * 4;
        uint4 t0 = *(const uint4*)(Hb + r0 * 128 + ((grp ^ kk0) << 4));
        uint4 t1 = *(const uint4*)(Hb + r1 * 128 + ((grp ^ kk1) << 4));
        uint4 t2 = *(const uint4*)(Hb + r2 * 128 + ((grp ^ kk0) << 4));
        const u32* p0 = (const u32*)&t0;
        const u32* p1 = (const u32*)&t1;
        const u32* p2 = (const u32*)&t2;
        u32 ow[4];
#pragma unroll
        for (int pp = 0; pp < 4; ++pp) {
          float vv[2];
#pragma unroll
          for (int hi = 0; hi < 2; ++hi) {
            const int e = pp * 2 + hi;
            float4 dv = *(const float4*)(&dwdb[(kt * 64 + grp * 8 + e) * 4]);
            u32 a0 = hi ? (p0[pp] >> 16) : (p0[pp] & 0xffffu);
            u32 a1 = hi ? (p1[pp] >> 16) : (p1[pp] & 0xffffu);
            u32 a2b = hi ? (p2[pp] >> 16) : (p2[pp] & 0xffffu);
            float nh0 = (bf2f(a0) - m0) * q0;
            float nh1 = (bf2f(a1) - mA) * qA;
            float nh2 = (bf2f(a2b) - mB) * qB;
            float v = fmaf(dv.x, nh0, fmaf(dv.y, nh1, fmaf(dv.z, nh2, dv.w)));
            vv[hi] = v >= 0.f ? v : a2v * v;
          }
          ow[pp] = f2bf(vv[0]) | (f2bf(vv[1]) << 16);
        }
        uint4 st; st.x = ow[0]; st.y = ow[1]; st.z = ow[2]; st.w = ow[3];
        *(uint4*)(Gb + ln * 128 + ((grp ^ (ln & 7)) << 4)) = st;
      }
    }
    __syncthreads();               // G visible; A(kt) drained
    if (kt < 7) stageH(kt + 1);    // overlaps MFMA below
    // ---- GEMM(kt) ----
#pragma unroll
    for (int ks = 0; ks < 2; ++ks) {
      bf16x8 bfr[4];
#pragma unroll
      for (int cf = 0; cf < 4; ++cf) {
        int brow = cf * 16 + ln15;
        int off = ((ks * 64 + lq * 16) ^ ((brow & 7) << 4));
        bfr[cf] = *(const bf16x8*)(Gb + brow * 128 + off);
      }
#pragma unroll
      for (int rf = 0; rf < 4; ++rf) {
        int arow = c0w + rf * 16 + ln15;
        int aoff = ((ks * 64 + lq * 16) ^ ((arow & 7) << 4));
        bf16x8 afr = *(const bf16x8*)(Ab + arow * 128 + aoff);
#pragma unroll
        for (int cf = 0; cf < 4; ++cf)
          acc[rf][cf] = __builtin_amdgcn_mfma_f32_16x16x32_bf16(afr, bfr[cf], acc[rf][cf], 0, 0, 0);
      }
    }
    __syncthreads();               // GEMM done (A free), H(kt+1) drained
    if (kt < 7) stageA(kt + 1);    // overlaps next computeG
  }

  // ---- epilogue: fold cln2 + biases, stage 32KB halves in Ab, coalesced stores ----
  float wsr[4][4], bir[4][4];
#pragma unroll
  for (int rf = 0; rf < 4; ++rf)
#pragma unroll
    for (int r = 0; r < 4; ++r) {
      int c = c0w + rf * 16 + lq * 4 + r;
      wsr[rf][r] = Wsum[c];
      bir[rf][r] = (c < Cn) ? bout[c] : bskip[c - Cn];
    }
  const size_t OUTOFF = (size_t)Bn * Cn * Ln;
  char* stg = Ab;
#pragma unroll
  for (int p = 0; p < 2; ++p) {
    if (p) __syncthreads();        // previous store pass done
#pragma unroll
    for (int cc = 0; cc < 2; ++cc) {
      const int cf = p * 2 + cc;
      const int ll = cc * 16 + ln15;        // 0..31
      const int l = l0 + cf * 16 + ln15;
      const float m2 = mean2[b * Ln + l];
      const float r2 = rstd2[b * Ln + l];
#pragma unroll
      for (int rf = 0; rf < 4; ++rf) {
#pragma unroll
        for (int r = 0; r < 4; ++r) {
          int c = c0w + rf * 16 + lq * 4 + r;
          float o = r2 * (acc[rf][cf][r] - m2 * wsr[rf][r]) + bir[rf][r];
          *(float*)(stg + c * 128 + ((((ll >> 2) ^ (c & 7)) << 4)) + (ll & 3) * 4) = o;
        }
      }
    }
    __syncthreads();
#pragma unroll
    for (int pp = 0; pp < 8; ++pp) {
      int i = pp * 256 + tid;
      int c = i >> 3, j = i & 7;
      float4 v = *(const float4*)(stg + c * 128 + (((j ^ (c & 7)) << 4)));
      int lcol = l0 + p * 32 + j * 4;
      if (c < Cn) {
        float4 xv = *(const float4*)(x + ((size_t)(b * Cn + c)) * Ln + lcol);
        v.x += xv.x; v.y += xv.y; v.z += xv.z; v.w += xv.w;
        *(float4*)(outp + ((size_t)(b * Cn + c)) * Ln + lcol) = v;
      } else {
        *(float4*)(outp + OUTOFF + ((size_t)(b * Cn + c - Cn)) * Ln + lcol) = v;
      }
    }
  }
}

extern "C" void kernel_launch(void* const* d_in, const int* in_sizes, int n_in,
                              void* d_out, int out_size, void* d_ws, size_t ws_size,
                              hipStream_t stream)
{
  const float* x     = (const float*)d_in[0];
  const float* W1    = (const float*)d_in[1];
  const float* b1    = (const float*)d_in[2];
  const float* dw    = (const float*)d_in[3];
  const float* db    = (const float*)d_in[4];
  const float* Wout  = (const float*)d_in[5];
  const float* bout  = (const float*)d_in[6];
  const float* Wskip = (const float*)d_in[7];
  const float* bskip = (const float*)d_in[8];
  const float* a1    = (const float*)d_in[9];
  const float* a2    = (const float*)d_in[10];
  float* outp = (float*)d_out;

  char* ws = (char*)d_ws;
  u16* hT     = (u16*)(ws);                  // 32,768,000 B
  u16* W1b    = (u16*)(ws + 65536000);       // 131,072 B
  u16* Wcatb  = (u16*)(ws + 65667072);       // 262,144 B
  float* Wsum   = (float*)(ws + 65929216);   // 1,024 B
  float* sum1   = (float*)(ws + 65930240);
  float* sumsq1 = (float*)(ws + 66058240);
  float* mean1  = (float*)(ws + 66186240);
  float* rstd1  = (float*)(ws + 66314240);
  float* sum2   = (float*)(ws + 66442240);
  float* sumsq2 = (float*)(ws + 66570240);
  float* mean2  = (float*)(ws + 66698240);
  float* rstd2  = (float*)(ws + 66826240);
  (void)in_sizes; (void)n_in; (void)out_size; (void)ws_size;

  hipLaunchKernelGGL(k0_prep, dim3(193), dim3(256), 0, stream,
                     W1, Wout, Wskip, W1b, Wcatb, Wsum);
  hipLaunchKernelGGL(k1_fused, dim3(Bn * 125), dim3(256), 0, stream,
                     x, W1b, b1, a1, hT, sum1, sumsq1);
  hipLaunchKernelGGL(k2_scan, dim3(Bn), dim3(256), 0, stream,
                     sum1, sumsq1, mean1, rstd1);
  hipLaunchKernelGGL(k3_sums, dim3(Bn * 125), dim3(256), 0, stream,
                     hT, mean1, rstd1, dw, db, a2, sum2, sumsq2);
  hipLaunchKernelGGL(k2_scan, dim3(Bn), dim3(256), 0, stream,
                     sum2, sumsq2, mean2, rstd2);
  hipLaunchKernelGGL(k5_fused, dim3(Bn * 125), dim3(256), 0, stream,
                     hT, Wcatb, Wsum, bout, bskip, mean1, rstd1, mean2, rstd2,
                     dw, db, a2, x, outp);
}

// Round 6
// 92.481 us; speedup vs baseline: 1.0409x; 1.0370x over previous
//
#include <hip/hip_runtime.h>

typedef unsigned short u16;
typedef unsigned int u32;
typedef __attribute__((ext_vector_type(8))) short bf16x8;
typedef __attribute__((ext_vector_type(4))) float f32x4;

#define Bn 4
#define Cn 128
#define Hn 512
#define Ln 8000
#define EPSf 1e-8f

__device__ __forceinline__ float bf2f(u32 v) { return __uint_as_float(v << 16); }
__device__ __forceinline__ u32 f2bf(float f) {
  u32 u = __float_as_uint(f);
  return (u + 0x7fffu + ((u >> 16) & 1u)) >> 16;
}
__device__ __forceinline__ void gl16(const void* g, void* l) {
  __builtin_amdgcn_global_load_lds((const __attribute__((address_space(1))) u32*)g,
                                   (__attribute__((address_space(3))) u32*)l, 16, 0, 0);
}

// ---------------- k0: weight prep (bf16 + pre-swizzled images) ----------------
// W1b:  image [512 h][128 k] bf16, elem (h,k) at byte h*256 + ((k*2)^((h&7)<<4))
// Wcatb: per K-tile kt(8): [256 c][64 kk] bf16, byte kt*32768 + c*128 + ((kk*2)^((c&7)<<4))
__global__ void k0_prep(const float* __restrict__ W1, const float* __restrict__ Wout,
                        const float* __restrict__ Wskip,
                        u16* __restrict__ W1b, u16* __restrict__ Wcatb,
                        float* __restrict__ Wsum)
{
  const int bid = blockIdx.x, tid = threadIdx.x;
  if (bid < 64) {
    const int base = (bid * 256 + tid) * 4;
#pragma unroll
    for (int t = 0; t < 4; ++t) {
      int i = base + t;            // 0..65535
      int h = i >> 7, k = i & 127;
      int dbyte = h * 256 + (((k * 2) ^ ((h & 7) << 4)));
      W1b[dbyte >> 1] = (u16)f2bf(W1[h * Cn + k]);
    }
  } else if (bid < 192) {
    const int base = ((bid - 64) * 256 + tid) * 4;
#pragma unroll
    for (int t = 0; t < 4; ++t) {
      int j = base + t;            // 0..131071
      int kt = j >> 14, r = j & 16383, c = r >> 6, kk = r & 63;
      int k = kt * 64 + kk;
      float v = (c < Cn) ? Wout[c * Hn + k] : Wskip[(c - Cn) * Hn + k];
      int dbyte = kt * 32768 + c * 128 + (((kk * 2) ^ ((c & 7) << 4)));
      Wcatb[dbyte >> 1] = (u16)f2bf(v);
    }
  } else {
    const int c = tid;
    const float* Wp = (c < Cn) ? (Wout + (size_t)c * Hn) : (Wskip + (size_t)(c - Cn) * Hn);
    float s = 0.f;
    for (int k = 0; k < Hn; ++k) s += Wp[k];
    Wsum[c] = s;
  }
}

// ---------------- k1: fused transpose + GEMM1 (h = prelu(W1@x+b1)) ----------------
// LDS 50 KB -> 3 blocks/CU. Store staging aliases regA (extra barrier per slice).
__global__ __launch_bounds__(256, 3)
void k1_fused(const float* __restrict__ x, const u16* __restrict__ W1b,
              const float* __restrict__ b1, const float* __restrict__ a1p,
              u16* __restrict__ hT, float* __restrict__ sum1, float* __restrict__ sumsq1)
{
  __shared__ char regA[32768];   // x f32 tile [128 c][256B] -> W1 slice -> store staging
  __shared__ char xs[16384];     // [64 l][128 c bf16], 16B-unit swizzle by (l&7)
  __shared__ float b1s[512];
  const int bidx = blockIdx.x;
  const int b = bidx / 125, l0 = (bidx % 125) * 64;
  const int tid = threadIdx.x, ln = tid & 63, w = tid >> 6;
  const int ln15 = ln & 15, lq = ln >> 4;

  {
    const char* xb = (const char*)x + ((size_t)b * Cn * Ln + l0) * 4;
#pragma unroll
    for (int i = 0; i < 8; ++i) {
      int chunk = w * 8 + i;                     // 0..31, 4 c-rows each
      gl16(xb + (size_t)(chunk * 4 + (ln >> 4)) * (Ln * 4) + (ln & 15) * 16,
           regA + chunk * 1024);
    }
  }
  b1s[tid] = b1[tid];
  b1s[tid + 256] = b1[tid + 256];
  __syncthreads();
  // transpose regA -> xs (bf16, swizzled)
#pragma unroll
  for (int p = 0; p < 4; ++p) {
    int u = tid + p * 256;
    int l = u & 63, ui = u >> 6;                 // ui 0..15
    u32 pk[4];
#pragma unroll
    for (int pp = 0; pp < 4; ++pp) {
      int c0 = ui * 8 + pp * 2;
      float f0 = *(const float*)(regA + c0 * 256 + l * 4);
      float f1 = *(const float*)(regA + (c0 + 1) * 256 + l * 4);
      pk[pp] = f2bf(f0) | (f2bf(f1) << 16);
    }
    uint4 st; st.x = pk[0]; st.y = pk[1]; st.z = pk[2]; st.w = pk[3];
    *(uint4*)(xs + l * 256 + ((ui * 16) ^ ((l & 7) << 4))) = st;
  }

  const float a1v = a1p[0];
  float sAcc = 0.f, qAcc = 0.f;
  char* stg = regA;              // aliased staging (guarded by barriers)

  for (int s = 0; s < 4; ++s) {
    __syncthreads();               // regA free (transpose / previous stg reads done)
#pragma unroll
    for (int i = 0; i < 8; ++i) {
      int chunk = w * 8 + i;
      gl16((const char*)W1b + s * 32768 + chunk * 1024 + ln * 16, regA + chunk * 1024);
    }
    __syncthreads();               // slice staged (barrier drains vmcnt)

    f32x4 acc[8];
    const f32x4 z4 = {0.f, 0.f, 0.f, 0.f};
#pragma unroll
    for (int rf = 0; rf < 8; ++rf) acc[rf] = z4;
#pragma unroll
    for (int kf = 0; kf < 4; ++kf) {
      const int brow = w * 16 + ln15;
      bf16x8 bfr = *(const bf16x8*)(xs + brow * 256 +
                                    ((kf * 64 + lq * 16) ^ ((brow & 7) << 4)));
#pragma unroll
      for (int rf = 0; rf < 8; ++rf) {
        int arow = rf * 16 + ln15;
        bf16x8 afr = *(const bf16x8*)(regA + arow * 256 +
                                      ((kf * 64 + lq * 16) ^ ((arow & 7) << 4)));
        acc[rf] = __builtin_amdgcn_mfma_f32_16x16x32_bf16(afr, bfr, acc[rf], 0, 0, 0);
      }
    }
    __syncthreads();               // ALL MFMA reads of regA done -> safe to reuse as stg

    // epilogue: bias + prelu + sums; pack to stg (wave-private, swizzled)
#pragma unroll
    for (int rf = 0; rf < 8; ++rf) {
      int hb = s * 128 + rf * 16 + lq * 4;
      float v0 = acc[rf][0] + b1s[hb + 0]; v0 = v0 >= 0.f ? v0 : a1v * v0;
      float v1 = acc[rf][1] + b1s[hb + 1]; v1 = v1 >= 0.f ? v1 : a1v * v1;
      float v2 = acc[rf][2] + b1s[hb + 2]; v2 = v2 >= 0.f ? v2 : a1v * v2;
      float v3 = acc[rf][3] + b1s[hb + 3]; v3 = v3 >= 0.f ? v3 : a1v * v3;
      sAcc += v0 + v1 + v2 + v3;
      qAcc += v0 * v0 + v1 * v1 + v2 * v2 + v3 * v3;
      uint2 st2;
      st2.x = f2bf(v0) | (f2bf(v1) << 16);
      st2.y = f2bf(v2) | (f2bf(v3) << 16);
      *(uint2*)(stg + w * 4096 + ln15 * 256 +
                ((rf * 32 + lq * 8) ^ ((ln15 & 3) << 4))) = st2;
    }
    // coalesced 256B-chunk stores of wave's 16 rows
#pragma unroll
    for (int p = 0; p < 4; ++p) {
      int lr = p * 4 + (ln >> 4);
      int j = ln & 15;
      uint4 v = *(const uint4*)(stg + w * 4096 + lr * 256 + ((j * 16) ^ ((lr & 3) << 4)));
      *(uint4*)((char*)hT + ((size_t)(b * Ln + l0 + w * 16 + lr)) * 1024 +
                s * 256 + j * 16) = v;
    }
  }
  // per-l sums: reduce over the 4 lq lanes
  sAcc += __shfl_xor(sAcc, 16); qAcc += __shfl_xor(qAcc, 16);
  sAcc += __shfl_xor(sAcc, 32); qAcc += __shfl_xor(qAcc, 32);
  if (lq == 0) {
    sum1[b * Ln + l0 + w * 16 + ln15] = sAcc;
    sumsq1[b * Ln + l0 + w * 16 + ln15] = qAcc;
  }
}

// ---------------- k2: causal scan -> mean/rstd (single-pass, register-blocked) ----------------
__global__ void k2_scan(const float* __restrict__ sum, const float* __restrict__ sumsq,
                        float* __restrict__ mean, float* __restrict__ rstd)
{
  const int b = blockIdx.x, tid = threadIdx.x;
  const int lane = tid & 63, w = tid >> 6;
  __shared__ float wts[4], wtq[4];
  float v[32], q[32];
  float ts = 0.f, tq = 0.f;
  const int base = tid * 32;                    // threads 0..249 cover 8000
  const bool act = (tid < 250);
  if (act) {
#pragma unroll
    for (int i = 0; i < 8; ++i) {
      float4 a = *(const float4*)(sum + (size_t)b * Ln + base + i * 4);
      float4 c = *(const float4*)(sumsq + (size_t)b * Ln + base + i * 4);
      v[i * 4 + 0] = a.x; v[i * 4 + 1] = a.y; v[i * 4 + 2] = a.z; v[i * 4 + 3] = a.w;
      q[i * 4 + 0] = c.x; q[i * 4 + 1] = c.y; q[i * 4 + 2] = c.z; q[i * 4 + 3] = c.w;
    }
#pragma unroll
    for (int i = 0; i < 32; ++i) { ts += v[i]; tq += q[i]; }
  }
  float is = ts, iq = tq;
#pragma unroll
  for (int off = 1; off < 64; off <<= 1) {
    float a = __shfl_up(is, off);
    float c = __shfl_up(iq, off);
    if (lane >= off) { is += a; iq += c; }
  }
  float es = is - ts, eq = iq - tq;             // exclusive prefix within wave
  if (lane == 63) { wts[w] = is; wtq[w] = iq; }
  __syncthreads();
  for (int ww = 0; ww < w; ++ww) { es += wts[ww]; eq += wtq[ww]; }
  if (act) {
    float rs = es, rq = eq;
#pragma unroll
    for (int i = 0; i < 32; ++i) {
      rs += v[i]; rq += q[i];
      float cnt = 512.f * (float)(base + i + 1);
      float mn = rs / cnt;
      float var = fmaxf(rq / cnt - mn * mn, 0.f);
      v[i] = mn;
      q[i] = rsqrtf(var + EPSf);
    }
#pragma unroll
    for (int i = 0; i < 8; ++i) {
      float4 a; a.x = v[i*4+0]; a.y = v[i*4+1]; a.z = v[i*4+2]; a.w = v[i*4+3];
      float4 c; c.x = q[i*4+0]; c.y = q[i*4+1]; c.z = q[i*4+2]; c.w = q[i*4+3];
      *(float4*)(mean + (size_t)b * Ln + base + i * 4) = a;
      *(float4*)(rstd + (size_t)b * Ln + base + i * 4) = c;
    }
  }
}

// ---------------- k3: g = prelu(dwconv(cln1(h))); hT -> gT (row-XOR swizzled) + sums ----------------
// 32-l tiles, hTs 40 KB -> 3 blocks/CU, grid Bn*250
__global__ __launch_bounds__(256, 3)
void k3_conv(const u16* __restrict__ hT, const float* __restrict__ mean1,
             const float* __restrict__ rstd1, const float* __restrict__ dw,
             const float* __restrict__ db, const float* __restrict__ a2p,
             u16* __restrict__ gT, float* __restrict__ sum2, float* __restrict__ sumsq2)
{
  __shared__ char hTs[40960];       // 40 rows x 1KB
  __shared__ float m1s[40], r1s[40];
  const int bidx = blockIdx.x;
  const int b = bidx / 250;
  const int l0 = (bidx % 250) * 32;
  const int tid = threadIdx.x;
  const int ln = tid & 63, w = tid >> 6;

  for (int i = 0; i < 10; ++i) {
    int chunk = w * 10 + i;
    int lr = l0 - 4 + chunk;
    int lc = lr < 0 ? 0 : (lr > Ln - 1 ? Ln - 1 : lr);
    gl16((const char*)hT + ((size_t)(b * Ln + lc)) * 1024 + ln * 16, hTs + chunk * 1024);
  }
  if (tid < 40) {
    int lr = l0 - 4 + tid;
    bool ok = (lr >= 0) && (lr < Ln);
    m1s[tid] = ok ? mean1[b * Ln + lr] : 0.f;
    r1s[tid] = ok ? rstd1[b * Ln + lr] : 0.f;
  }
  float d0[8], d1[8], d2[8], dbv[8];
#pragma unroll
  for (int e = 0; e < 8; ++e) {
    int hh = ln * 8 + e;
    d0[e] = dw[hh * 3 + 0]; d1[e] = dw[hh * 3 + 1]; d2[e] = dw[hh * 3 + 2];
    dbv[e] = db[hh];
  }
  const float a2v = a2p[0];
  __syncthreads();

  for (int it = 0; it < 8; ++it) {
    const int llo = w * 8 + it;       // local out row 0..31
    const int l = l0 + llo;
    uint4 t0 = *reinterpret_cast<const uint4*>(hTs + (size_t)(llo) * 1024 + ln * 16);
    uint4 t1 = *reinterpret_cast<const uint4*>(hTs + (size_t)(llo + 4) * 1024 + ln * 16);
    uint4 t2 = *reinterpret_cast<const uint4*>(hTs + (size_t)(llo + 8) * 1024 + ln * 16);
    const float m0 = m1s[llo],     rr0 = r1s[llo];
    const float mC = m1s[llo + 4], rrC = r1s[llo + 4];
    const float m2v = m1s[llo + 8], rr2 = r1s[llo + 8];
    const u32* p0 = reinterpret_cast<const u32*>(&t0);
    const u32* p1 = reinterpret_cast<const u32*>(&t1);
    const u32* p2 = reinterpret_cast<const u32*>(&t2);
    float sv = 0.f, qv = 0.f;
    u32 outw[4];
#pragma unroll
    for (int pp = 0; pp < 4; ++pp) {
      float v01[2];
#pragma unroll
      for (int hi = 0; hi < 2; ++hi) {
        int e = pp * 2 + hi;
        u32 a0 = hi ? (p0[pp] >> 16) : (p0[pp] & 0xffffu);
        u32 a1b = hi ? (p1[pp] >> 16) : (p1[pp] & 0xffffu);
        u32 a2b = hi ? (p2[pp] >> 16) : (p2[pp] & 0xffffu);
        float nh0 = (bf2f(a0) - m0) * rr0;
        float nh1 = (bf2f(a1b) - mC) * rrC;
        float nh2 = (bf2f(a2b) - m2v) * rr2;
        float vv = fmaf(d0[e], nh0, fmaf(d1[e], nh1, fmaf(d2[e], nh2, dbv[e])));
        vv = vv >= 0.f ? vv : a2v * vv;
        sv += vv; qv += vv * vv;
        v01[hi] = vv;
      }
      outw[pp] = f2bf(v01[0]) | (f2bf(v01[1]) << 16);
    }
    uint4 st; st.x = outw[0]; st.y = outw[1]; st.z = outw[2]; st.w = outw[3];
    *reinterpret_cast<uint4*>((char*)gT + ((size_t)(b * Ln + l)) * 1024 +
                              (((ln * 16) ^ ((l & 7) << 4)))) = st;
#pragma unroll
    for (int off = 1; off < 64; off <<= 1) {
      sv += __shfl_xor(sv, off);
      qv += __shfl_xor(qv, off);
    }
    if (ln == 0) {
      sum2[b * Ln + l] = sv;
      sumsq2[b * Ln + l] = qv;
    }
  }
}

// ---------------- k5: out/skip = Wcat@g (MFMA) + folded cln2 + residual ----------------
// single-buffered A (L2-resident Wcat), dbuf B; LDS 48 KB -> 3 blocks/CU
__global__ __launch_bounds__(256, 3)
void k5_gemm2(const u16* __restrict__ gT, const u16* __restrict__ Wcatb,
              const float* __restrict__ Wsum, const float* __restrict__ bout,
              const float* __restrict__ bskip, const float* __restrict__ mean2,
              const float* __restrict__ rstd2, const float* __restrict__ x,
              float* __restrict__ outp)
{
  __shared__ char Ab[32768];
  __shared__ char Bb[2][8192];
  const int bidx = blockIdx.x;
  const int b = bidx / 125;
  const int l0 = (bidx % 125) * 64;
  const int tid = threadIdx.x;
  const int ln = tid & 63, w = tid >> 6;
  const int ln15 = ln & 15, lq = ln >> 4;

  auto stageA = [&](int kt) {
    const char* Asrc = (const char*)Wcatb + kt * 32768;
#pragma unroll
    for (int i = 0; i < 8; ++i) {
      int chunk = w * 8 + i;
      gl16(Asrc + chunk * 1024 + ln * 16, Ab + chunk * 1024);
    }
  };
  auto stageB = [&](int kt, int bi) {
#pragma unroll
    for (int j = 0; j < 2; ++j) {
      int chunk = w * 2 + j;
      int lrow = chunk * 8 + (ln >> 3);
      int pos = (ln & 7) * 16;
      gl16((const char*)gT + ((size_t)(b * Ln + l0 + lrow)) * 1024 + kt * 128 + pos,
           Bb[bi] + chunk * 1024);
    }
  };

  f32x4 acc[4][4];
  const f32x4 z4 = {0.f, 0.f, 0.f, 0.f};
#pragma unroll
  for (int i = 0; i < 4; ++i)
#pragma unroll
    for (int j = 0; j < 4; ++j) acc[i][j] = z4;

  const int c0w = w * 64;
  stageA(0);
  stageB(0, 0);
  __syncthreads();
  for (int kt = 0; kt < 8; ++kt) {
    const int cur = kt & 1;
    if (kt < 7) stageB(kt + 1, cur ^ 1);      // drains at barrier below
#pragma unroll
    for (int ks = 0; ks < 2; ++ks) {
      bf16x8 bfr[4];
#pragma unroll
      for (int cf = 0; cf < 4; ++cf) {
        int brow = cf * 16 + ln15;
        int off = ((ks * 64 + lq * 16) ^ ((brow & 7) << 4));
        bfr[cf] = *reinterpret_cast<const bf16x8*>(Bb[cur] + brow * 128 + off);
      }
#pragma unroll
      for (int rf = 0; rf < 4; ++rf) {
        int arow = c0w + rf * 16 + ln15;
        int aoff = ((ks * 64 + lq * 16) ^ ((arow & 7) << 4));
        bf16x8 afr = *reinterpret_cast<const bf16x8*>(Ab + arow * 128 + aoff);
#pragma unroll
        for (int cf = 0; cf < 4; ++cf)
          acc[rf][cf] = __builtin_amdgcn_mfma_f32_16x16x32_bf16(afr, bfr[cf], acc[rf][cf], 0, 0, 0);
      }
    }
    __syncthreads();                          // Ab reads done; B(kt+1) landed
    if (kt < 7) {
      stageA(kt + 1);
      __syncthreads();                        // A(kt+1) landed
    }
  }

  // fold cln2 + biases; stage f32 halves [256 c][32 l] into freed Ab (swizzled)
  float wsr[4][4], bir[4][4];
#pragma unroll
  for (int rf = 0; rf < 4; ++rf)
#pragma unroll
    for (int r = 0; r < 4; ++r) {
      int c = c0w + rf * 16 + lq * 4 + r;
      wsr[rf][r] = Wsum[c];
      bir[rf][r] = (c < Cn) ? bout[c] : bskip[c - Cn];
    }
  const size_t OUTOFF = (size_t)Bn * Cn * Ln;
  char* stg = Ab;
#pragma unroll
  for (int p = 0; p < 2; ++p) {
    if (p) __syncthreads();        // previous store pass done
#pragma unroll
    for (int cc = 0; cc < 2; ++cc) {
      const int cf = p * 2 + cc;
      const int ll = cc * 16 + ln15;        // 0..31
      const int l = l0 + cf * 16 + ln15;
      const float m2 = mean2[b * Ln + l];
      const float r2 = rstd2[b * Ln + l];
#pragma unroll
      for (int rf = 0; rf < 4; ++rf) {
#pragma unroll
        for (int r = 0; r < 4; ++r) {
          int c = c0w + rf * 16 + lq * 4 + r;
          float o = r2 * (acc[rf][cf][r] - m2 * wsr[rf][r]) + bir[rf][r];
          *(float*)(stg + c * 128 + ((((ll >> 2) ^ (c & 7)) << 4)) + (ll & 3) * 4) = o;
        }
      }
    }
    __syncthreads();
#pragma unroll
    for (int pp = 0; pp < 8; ++pp) {
      int i = pp * 256 + tid;
      int c = i >> 3, j = i & 7;
      float4 v = *(const float4*)(stg + c * 128 + (((j ^ (c & 7)) << 4)));
      int lcol = l0 + p * 32 + j * 4;
      if (c < Cn) {
        float4 xv = *(const float4*)(x + ((size_t)(b * Cn + c)) * Ln + lcol);
        v.x += xv.x; v.y += xv.y; v.z += xv.z; v.w += xv.w;
        *(float4*)(outp + ((size_t)(b * Cn + c)) * Ln + lcol) = v;
      } else {
        *(float4*)(outp + OUTOFF + ((size_t)(b * Cn + c - Cn)) * Ln + lcol) = v;
      }
    }
  }
}

extern "C" void kernel_launch(void* const* d_in, const int* in_sizes, int n_in,
                              void* d_out, int out_size, void* d_ws, size_t ws_size,
                              hipStream_t stream)
{
  const float* x     = (const float*)d_in[0];
  const float* W1    = (const float*)d_in[1];
  const float* b1    = (const float*)d_in[2];
  const float* dw    = (const float*)d_in[3];
  const float* db    = (const float*)d_in[4];
  const float* Wout  = (const float*)d_in[5];
  const float* bout  = (const float*)d_in[6];
  const float* Wskip = (const float*)d_in[7];
  const float* bskip = (const float*)d_in[8];
  const float* a1    = (const float*)d_in[9];
  const float* a2    = (const float*)d_in[10];
  float* outp = (float*)d_out;

  char* ws = (char*)d_ws;
  u16* hT     = (u16*)(ws);                  // 32,768,000 B
  u16* gT     = (u16*)(ws + 32768000);       // 32,768,000 B
  u16* W1b    = (u16*)(ws + 65536000);       // 131,072 B
  u16* Wcatb  = (u16*)(ws + 65667072);       // 262,144 B
  float* Wsum   = (float*)(ws + 65929216);   // 1,024 B
  float* sum1   = (float*)(ws + 65930240);
  float* sumsq1 = (float*)(ws + 66058240);
  float* mean1  = (float*)(ws + 66186240);
  float* rstd1  = (float*)(ws + 66314240);
  float* sum2   = (float*)(ws + 66442240);
  float* sumsq2 = (float*)(ws + 66570240);
  float* mean2  = (float*)(ws + 66698240);
  float* rstd2  = (float*)(ws + 66826240);
  (void)in_sizes; (void)n_in; (void)out_size; (void)ws_size;

  hipLaunchKernelGGL(k0_prep, dim3(193), dim3(256), 0, stream,
                     W1, Wout, Wskip, W1b, Wcatb, Wsum);
  hipLaunchKernelGGL(k1_fused, dim3(Bn * 125), dim3(256), 0, stream,
                     x, W1b, b1, a1, hT, sum1, sumsq1);
  hipLaunchKernelGGL(k2_scan, dim3(Bn), dim3(256), 0, stream,
                     sum1, sumsq1, mean1, rstd1);
  hipLaunchKernelGGL(k3_conv, dim3(Bn * 250), dim3(256), 0, stream,
                     hT, mean1, rstd1, dw, db, a2, gT, sum2, sumsq2);
  hipLaunchKernelGGL(k2_scan, dim3(Bn), dim3(256), 0, stream,
                     sum2, sumsq2, mean2, rstd2);
  hipLaunchKernelGGL(k5_gemm2, dim3(Bn * 125), dim3(256), 0, stream,
                     gT, Wcatb, Wsum, bout, bskip, mean2, rstd2, x, outp);
}